// Round 7
// baseline (235.626 us; speedup 1.0000x reference)
//
#include <hip/hip_runtime.h>
#include <stdint.h>

#define NB 32768
#define NPASS 4
#define FULL27 0x07FFFFFFu
#define NWORDS (NB * 27)   // 884736 packed words

// layout: per puzzle, 27 words; word (d*3+b) = digit d, band b (rows 3b..3b+2),
// bit (r*9+c) with r = local row 0..2, c = column 0..8.
// BOX k mask within band: 0x1C0E07 << 3k ; COL c: 0x40201 << c ; ROW r: 0x1FF << 9r
// Packed word w == bits of input floats [27w .. 27w+26] (flat order matches).
// Note: word (d,b) of puzzle p covers CONTIGUOUS flat floats p*729 + d*81 + b*27 + (0..26).

// ---------------- PACK: wave ballot -> 64 words per wave (validated r4) ----------------
__global__ __launch_bounds__(256)
void pack_kernel(const uint32_t* __restrict__ in, uint32_t* __restrict__ packed) {
    __shared__ uint32_t pool[4][56];
    const int lane = threadIdx.x & 63;
    const int wv = threadIdx.x >> 6;
    const size_t wordBase = (size_t)blockIdx.x * 256 + (size_t)wv * 64;
    const uint32_t* src = in + wordBase * 27;
    #pragma unroll
    for (int i = 0; i < 27; ++i) {
        uint32_t v = src[(size_t)i * 64 + lane];
        unsigned long long m = __ballot(v != 0u);
        if (lane == 0) {
            pool[wv][2 * i]     = (uint32_t)m;
            pool[wv][2 * i + 1] = (uint32_t)(m >> 32);
        }
    }
    __syncthreads();
    const int bit = lane * 27;
    const int di = bit >> 5;
    uint64_t both = (uint64_t)pool[wv][di] | ((uint64_t)pool[wv][di + 1] << 32);
    packed[wordBase + lane] = (uint32_t)(both >> (bit & 31)) & FULL27;
}

__device__ __forceinline__ uint32_t colfold(uint32_t w) {
    return (w | (w >> 9) | (w >> 18)) & 0x1FFu;
}
__device__ __forceinline__ uint32_t colmaj2(uint32_t w) {   // columns with >=2 bits in band
    return ((w & (w >> 9)) | ((w | (w >> 9)) & (w >> 18))) & 0x1FFu;
}

// ---------------- SOLVE+EXPAND: 3 lanes/puzzle, shuffle exchanges, fused output ----------------
// Lane l: triple t = l/3 (puzzle), band = l%3. 21 puzzles/wave (lane 63 idle).
// Cross-band exchanges via __shfl (validated r6). Output phase: each wave
// round-trips its 21 puzzles' 729-bit results through a wave-private LDS slice
// (DS ops from one wave are pipe-ordered -> no barriers), then writes the float
// expansion with perfectly-coalesced stores. Stores are fire-and-forget, so
// 1564 waves suffice to drive the 95.6 MB write (r3's failure was loads).
__global__ __launch_bounds__(256, 1)
void solve_kernel(const uint32_t* __restrict__ pin, float* __restrict__ out,
                  float* __restrict__ solved) {
    __shared__ uint32_t pool[4][488];       // per-wave 488 dwords (21*729=15309 bits used)
    const int lane = threadIdx.x & 63;
    const int wv   = threadIdx.x >> 6;
    const int trip = lane / 3;              // 0..21 (21 = idle lane 63)
    const int band = lane - trip * 3;
    const int bo1 = band == 2 ? 0 : band + 1;
    const int bo2 = band == 0 ? 2 : band - 1;
    int sl1 = trip * 3 + bo1; if (sl1 > 63) sl1 = 63;   // partner lanes
    int sl2 = trip * 3 + bo2; if (sl2 > 63) sl2 = 63;
    const int pb = blockIdx.x * 84 + wv * 21;           // first puzzle of this wave
    const int p = pb + trip;
    const bool valid = (trip < 21) && (p < NB);
    const int pl = valid ? p : (NB - 1);    // clamped for loads

    uint32_t bd[9];
    {
        const uint32_t* src = pin + (size_t)pl * 27 + band;
        #pragma unroll
        for (int d = 0; d < 9; ++d) bd[d] = src[d * 3];
    }

    #pragma unroll 1
    for (int pass = 0; pass < NPASS; ++pass) {
        // ---------- filter 'box' (band-local) ----------
        {
            uint32_t on = 0, tw = 0, fo = 0;
            #pragma unroll
            for (int d = 0; d < 9; ++d) {
                uint32_t c = on & bd[d];
                on ^= bd[d]; fo |= tw & c; tw ^= c;
            }
            uint32_t ex1 = on & ~tw & ~fo;
            #pragma unroll
            for (int d = 0; d < 9; ++d) {
                uint32_t s = bd[d] & ex1;
                #pragma unroll
                for (int k = 0; k < 3; ++k) {
                    uint32_t bm = 0x1C0E07u << (3 * k);
                    uint32_t sm = s & bm;
                    uint32_t multi = sm & (sm - 1u);
                    uint32_t keep = (sm == 0u) ? 0xFFFFFFFFu : (~bm | (multi ? 0u : sm));
                    bd[d] &= keep;
                }
            }
        }

        // ---------- pointing 'h' (band-local) ----------
        #pragma unroll
        for (int d = 0; d < 9; ++d) {
            uint32_t w = bd[d];
            uint32_t t = (w | (w >> 1) | (w >> 2)) & 0x01249249u;
            uint32_t sum = (t & 0x1FFu) + ((t >> 9) & 0x1FFu) + ((t >> 18) & 0x1FFu);
            uint32_t single = sum & ~(sum >> 1) & 0x49u;
            uint32_t point = t & (single * 0x40201u);
            uint32_t clearm = 0;
            #pragma unroll
            for (int r = 0; r < 3; ++r) {
                uint32_t pr = (point >> (9 * r)) & 0x1FFu;
                uint32_t multi = pr & (pr - 1u);
                uint32_t segkeep = multi ? 0u : pr * 7u;
                uint32_t rc = pr ? ((0x1FFu & ~segkeep) << (9 * r)) : 0u;
                clearm |= rc;
            }
            bd[d] = w & ~clearm;
        }

        // ---------- pointing 'v' (cross-band via shuffle) ----------
        {
            uint32_t pnt[9];
            #pragma unroll
            for (int d = 0; d < 9; ++d) {
                uint32_t w = bd[d];
                uint32_t q = colfold(w);
                uint32_t u = (q & 0x49u) + ((q >> 1) & 0x49u) + ((q >> 2) & 0x49u);
                uint32_t single = u & ~(u >> 1) & 0x49u;
                pnt[d] = q & (single * 7u);
            }
            #pragma unroll
            for (int d = 0; d < 9; ++d) {
                uint32_t o = (uint32_t)__shfl((int)pnt[d], sl1, 64) |
                             (uint32_t)__shfl((int)pnt[d], sl2, 64);
                bd[d] &= ~(o * 0x40201u);
            }
        }

        // ---------- unique 'h' (band-local) ----------
        {
            uint32_t hid[9], has = 0;
            #pragma unroll
            for (int d = 0; d < 9; ++d) {
                uint32_t w = bd[d], h = 0;
                #pragma unroll
                for (int r = 0; r < 3; ++r) {
                    uint32_t x = w & (0x1FFu << (9 * r));
                    h |= (x & (x - 1u)) ? 0u : x;
                }
                hid[d] = h; has |= h;
            }
            #pragma unroll
            for (int d = 0; d < 9; ++d) bd[d] = (bd[d] & ~has) | hid[d];
        }

        // ---------- unique 'v' (cross-band via shuffle) ----------
        {
            uint32_t hid[9], has = 0;
            #pragma unroll
            for (int d = 0; d < 9; ++d) {
                uint32_t w = bd[d];
                uint32_t q0 = colfold(w), m0 = colmaj2(w);
                uint32_t ex = q0 | (m0 << 9);
                uint32_t ea = (uint32_t)__shfl((int)ex, sl1, 64);
                uint32_t eb = (uint32_t)__shfl((int)ex, sl2, 64);
                uint32_t qa = ea & 0x1FFu, ma = ea >> 9;
                uint32_t qb = eb & 0x1FFu, mb = eb >> 9;
                uint32_t ge2 = m0 | ma | mb | (q0 & qa) | (q0 & qb) | (qa & qb);
                uint32_t ex1c = (q0 | qa | qb) & ~ge2;   // column total count == 1
                hid[d] = w & ((ex1c & q0) * 0x40201u);
                has |= hid[d];
            }
            #pragma unroll
            for (int d = 0; d < 9; ++d) bd[d] = (bd[d] & ~has) | hid[d];
        }

        // ---------- unique 'box' (band-local) ----------
        {
            uint32_t hid[9], has = 0;
            #pragma unroll
            for (int d = 0; d < 9; ++d) {
                uint32_t w = bd[d], h = 0;
                #pragma unroll
                for (int k = 0; k < 3; ++k) {
                    uint32_t x = w & (0x1C0E07u << (3 * k));
                    h |= (x & (x - 1u)) ? 0u : x;
                }
                hid[d] = h; has |= h;
            }
            #pragma unroll
            for (int d = 0; d < 9; ++d) bd[d] = (bd[d] & ~has) | hid[d];
        }

        // ---------- doubles 'v' twice (cross-band via shuffle) ----------
        #pragma unroll 1
        for (int rep = 0; rep < 2; ++rep) {
            uint32_t on = 0, tw = 0, fo = 0;
            #pragma unroll
            for (int d = 0; d < 9; ++d) {
                uint32_t c = on & bd[d];
                on ^= bd[d]; fo |= tw & c; tw ^= c;
            }
            uint32_t ex2 = tw & ~on & ~fo;
            uint32_t Q[9], K[9];
            #pragma unroll
            for (int d = 0; d < 9; ++d) { Q[d] = bd[d] & ex2; K[d] = 0u; }
            #pragma unroll
            for (int d1 = 0; d1 < 9; ++d1)
                #pragma unroll
                for (int d2 = d1 + 1; d2 < 9; ++d2) {
                    uint32_t P = Q[d1] & Q[d2];
                    uint32_t f0 = colfold(P), g0 = colmaj2(P);
                    uint32_t ex = f0 | (g0 << 9);
                    uint32_t ea = (uint32_t)__shfl((int)ex, sl1, 64);
                    uint32_t eb = (uint32_t)__shfl((int)ex, sl2, 64);
                    uint32_t fa = ea & 0x1FFu, ga = ea >> 9;
                    uint32_t fb = eb & 0x1FFu, gb = eb >> 9;
                    // columns with >=2 exact-pair cells across the full column
                    uint32_t dup = g0 | ga | gb | (f0 & fa) | (f0 & fb) | (fa & fb);
                    uint32_t sK = P & (dup * 0x40201u);
                    K[d1] |= sK; K[d2] |= sK;
                }
            #pragma unroll
            for (int d = 0; d < 9; ++d) {
                uint32_t kc = colfold(K[d]);
                uint32_t cols = kc | (uint32_t)__shfl((int)kc, sl1, 64)
                                   | (uint32_t)__shfl((int)kc, sl2, 64);
                uint32_t em = cols * 0x40201u;
                bd[d] = (bd[d] & ~em) | K[d];
            }
        }

        // ---------- doubles 'box' (band-local) ----------
        {
            uint32_t on = 0, tw = 0, fo = 0;
            #pragma unroll
            for (int d = 0; d < 9; ++d) {
                uint32_t c = on & bd[d];
                on ^= bd[d]; fo |= tw & c; tw ^= c;
            }
            uint32_t ex2 = tw & ~on & ~fo;
            uint32_t Q[9], K[9];
            #pragma unroll
            for (int d = 0; d < 9; ++d) { Q[d] = bd[d] & ex2; K[d] = 0u; }
            #pragma unroll
            for (int d1 = 0; d1 < 9; ++d1)
                #pragma unroll
                for (int d2 = d1 + 1; d2 < 9; ++d2) {
                    uint32_t P = Q[d1] & Q[d2];
                    #pragma unroll
                    for (int k = 0; k < 3; ++k) {
                        uint32_t m = P & (0x1C0E07u << (3 * k));
                        uint32_t s = (m & (m - 1u)) ? m : 0u;
                        K[d1] |= s; K[d2] |= s;
                    }
                }
            #pragma unroll
            for (int d = 0; d < 9; ++d)
                #pragma unroll
                for (int k = 0; k < 3; ++k) {
                    uint32_t bm = 0x1C0E07u << (3 * k);
                    uint32_t t = K[d] & bm;
                    uint32_t mask = t ? (~bm | t) : 0xFFFFFFFFu;
                    bd[d] &= mask;
                }
        }
    } // passes

    // ---------------- solved flag (AND across triple via shuffle) ----------------
    {
        uint32_t on = 0, tw = 0, fo = 0;
        #pragma unroll
        for (int d = 0; d < 9; ++d) {
            uint32_t c = on & bd[d];
            on ^= bd[d]; fo |= tw & c; tw ^= c;
        }
        uint32_t okb = ((on & ~tw & ~fo) == FULL27) ? 1u : 0u;
        uint32_t all = okb & (uint32_t)__shfl((int)okb, sl1, 64)
                           & (uint32_t)__shfl((int)okb, sl2, 64);
        if (valid && band == 0) solved[p] = all ? 1.0f : 0.0f;
    }

    // ---------------- EXPAND (fused): wave-private LDS bit slice -> coalesced floats ----
    // DS ops from one wave execute in order; no __syncthreads needed (slice is
    // wave-private). Bit i of slice == float pb*729 + i of the output.
    {
        uint32_t* mypool = pool[wv];
        #pragma unroll
        for (int j = 0; j < 8; ++j) {
            int idx = j * 64 + lane;
            if (idx < 488) mypool[idx] = 0u;
        }
        if (valid) {
            #pragma unroll
            for (int d = 0; d < 9; ++d) {
                int bitbase = trip * 729 + d * 81 + band * 27;
                int di = bitbase >> 5;
                int sh = bitbase & 31;
                uint64_t both = (uint64_t)bd[d] << sh;
                atomicOr(&mypool[di], (uint32_t)both);
                atomicOr(&mypool[di + 1], (uint32_t)(both >> 32));
            }
        }
        int nv = NB - pb; if (nv > 21) nv = 21; if (nv < 0) nv = 0;
        const int limit = nv * 729;                    // <= 15309
        float* dst = out + (size_t)pb * 729;
        #pragma unroll 4
        for (int i = 0; i < 240; ++i) {
            int idx = i * 64 + lane;
            if (idx < limit) {
                uint32_t w = mypool[idx >> 5];
                dst[idx] = (float)((w >> (idx & 31)) & 1u);
            }
        }
    }
}

extern "C" void kernel_launch(void* const* d_in, const int* in_sizes, int n_in,
                              void* d_out, int out_size, void* d_ws, size_t ws_size,
                              hipStream_t stream) {
    const uint32_t* in = (const uint32_t*)d_in[0];   // float32 bits; nonzero <=> 1.0f
    float* out = (float*)d_out;
    float* solved = out + (size_t)NB * 729;
    uint32_t* packed = (uint32_t*)d_ws;              // NWORDS words = 3.54 MB

    pack_kernel<<<NWORDS / 256, 256, 0, stream>>>(in, packed);          // 3456 blocks
    // 84 puzzles per 256-thread block (21 per wave) -> ceil(32768/84) = 391 blocks
    solve_kernel<<<(NB + 83) / 84, 256, 0, stream>>>(packed, out, solved);
}

// Round 8
// 227.596 us; speedup vs baseline: 1.0353x; 1.0353x over previous
//
#include <hip/hip_runtime.h>
#include <stdint.h>

#define NB 32768
#define NPASS 4
#define FULL27 0x07FFFFFFu
#define NWORDS (NB * 27)   // 884736 packed words

// layout: per puzzle, 27 words; word (d*3+b) = digit d, band b (rows 3b..3b+2),
// bit (r*9+c) with r = local row 0..2, c = column 0..8.
// BOX k mask within band: 0x1C0E07 << 3k ; COL c: 0x40201 << c ; ROW r: 0x1FF << 9r
// Packed word w == bits of input floats [27w .. 27w+26] (flat order matches).
// Word (d,b) of puzzle p covers CONTIGUOUS flat floats p*729 + d*81 + b*27 + (0..26).

// ---------------- PACK: wave ballot -> 64 words per wave (validated r4) ----------------
__global__ __launch_bounds__(256)
void pack_kernel(const uint32_t* __restrict__ in, uint32_t* __restrict__ packed) {
    __shared__ uint32_t pool[4][56];
    const int lane = threadIdx.x & 63;
    const int wv = threadIdx.x >> 6;
    const size_t wordBase = (size_t)blockIdx.x * 256 + (size_t)wv * 64;
    const uint32_t* src = in + wordBase * 27;
    #pragma unroll
    for (int i = 0; i < 27; ++i) {
        uint32_t v = src[(size_t)i * 64 + lane];
        unsigned long long m = __ballot(v != 0u);
        if (lane == 0) {
            pool[wv][2 * i]     = (uint32_t)m;
            pool[wv][2 * i + 1] = (uint32_t)(m >> 32);
        }
    }
    __syncthreads();
    const int bit = lane * 27;
    const int di = bit >> 5;
    uint64_t both = (uint64_t)pool[wv][di] | ((uint64_t)pool[wv][di + 1] << 32);
    packed[wordBase + lane] = (uint32_t)(both >> (bit & 31)) & FULL27;
}

__device__ __forceinline__ uint32_t colfold(uint32_t w) {
    return (w | (w >> 9) | (w >> 18)) & 0x1FFu;
}
__device__ __forceinline__ uint32_t colmaj2(uint32_t w) {   // columns with >=2 bits in band
    return ((w & (w >> 9)) | ((w | (w >> 9)) & (w >> 18))) & 0x1FFu;
}

// ---------------- SOLVE+EXPAND: 3 lanes/puzzle, shuffle exchanges, block-pool output ----
// Lane l: triple t = l/3 (puzzle), band = l%3. 21 puzzles/wave (lane 63 idle).
// Cross-band exchanges via __shfl (validated r6). Output: all waves OR result
// bits into ONE block-level pool (84 puzzles x 729 bits = 1914 dwords), then the
// whole block expands with float4 stores (block window = 61236 floats: divisible
// by 4 and 16B-aligned; per-wave 21*729 was odd -> scalar-only). 2 barriers total.
__global__ __launch_bounds__(256, 1)
void solve_kernel(const uint32_t* __restrict__ pin, float* __restrict__ out,
                  float* __restrict__ solved) {
    __shared__ uint32_t bpool[1914];        // 84 * 729 bits = 61236 bits
    const int lane = threadIdx.x & 63;
    const int wv   = threadIdx.x >> 6;
    const int trip = lane / 3;              // 0..21 (21 = idle lane 63)
    const int band = lane - trip * 3;
    const int bo1 = band == 2 ? 0 : band + 1;
    const int bo2 = band == 0 ? 2 : band - 1;
    int sl1 = trip * 3 + bo1; if (sl1 > 63) sl1 = 63;   // partner lanes
    int sl2 = trip * 3 + bo2; if (sl2 > 63) sl2 = 63;
    const int blockP = blockIdx.x * 84;                 // first puzzle of block
    const int p = blockP + wv * 21 + trip;
    const bool valid = (trip < 21) && (p < NB);
    const int pl = valid ? p : (NB - 1);    // clamped for loads

    uint32_t bd[9];
    {
        const uint32_t* src = pin + (size_t)pl * 27 + band;
        #pragma unroll
        for (int d = 0; d < 9; ++d) bd[d] = src[d * 3];
    }

    #pragma unroll 1
    for (int pass = 0; pass < NPASS; ++pass) {
        // ---------- filter 'box' (band-local) ----------
        {
            uint32_t on = 0, tw = 0, fo = 0;
            #pragma unroll
            for (int d = 0; d < 9; ++d) {
                uint32_t c = on & bd[d];
                on ^= bd[d]; fo |= tw & c; tw ^= c;
            }
            uint32_t ex1 = on & ~tw & ~fo;
            #pragma unroll
            for (int d = 0; d < 9; ++d) {
                uint32_t s = bd[d] & ex1;
                #pragma unroll
                for (int k = 0; k < 3; ++k) {
                    uint32_t bm = 0x1C0E07u << (3 * k);
                    uint32_t sm = s & bm;
                    uint32_t multi = sm & (sm - 1u);
                    uint32_t keep = (sm == 0u) ? 0xFFFFFFFFu : (~bm | (multi ? 0u : sm));
                    bd[d] &= keep;
                }
            }
        }

        // ---------- pointing 'h' (band-local) ----------
        #pragma unroll
        for (int d = 0; d < 9; ++d) {
            uint32_t w = bd[d];
            uint32_t t = (w | (w >> 1) | (w >> 2)) & 0x01249249u;
            uint32_t sum = (t & 0x1FFu) + ((t >> 9) & 0x1FFu) + ((t >> 18) & 0x1FFu);
            uint32_t single = sum & ~(sum >> 1) & 0x49u;
            uint32_t point = t & (single * 0x40201u);
            uint32_t clearm = 0;
            #pragma unroll
            for (int r = 0; r < 3; ++r) {
                uint32_t pr = (point >> (9 * r)) & 0x1FFu;
                uint32_t multi = pr & (pr - 1u);
                uint32_t segkeep = multi ? 0u : pr * 7u;
                uint32_t rc = pr ? ((0x1FFu & ~segkeep) << (9 * r)) : 0u;
                clearm |= rc;
            }
            bd[d] = w & ~clearm;
        }

        // ---------- pointing 'v' (cross-band via shuffle) ----------
        {
            uint32_t pnt[9];
            #pragma unroll
            for (int d = 0; d < 9; ++d) {
                uint32_t w = bd[d];
                uint32_t q = colfold(w);
                uint32_t u = (q & 0x49u) + ((q >> 1) & 0x49u) + ((q >> 2) & 0x49u);
                uint32_t single = u & ~(u >> 1) & 0x49u;
                pnt[d] = q & (single * 7u);
            }
            #pragma unroll
            for (int d = 0; d < 9; ++d) {
                uint32_t o = (uint32_t)__shfl((int)pnt[d], sl1, 64) |
                             (uint32_t)__shfl((int)pnt[d], sl2, 64);
                bd[d] &= ~(o * 0x40201u);
            }
        }

        // ---------- unique 'h' (band-local) ----------
        {
            uint32_t hid[9], has = 0;
            #pragma unroll
            for (int d = 0; d < 9; ++d) {
                uint32_t w = bd[d], h = 0;
                #pragma unroll
                for (int r = 0; r < 3; ++r) {
                    uint32_t x = w & (0x1FFu << (9 * r));
                    h |= (x & (x - 1u)) ? 0u : x;
                }
                hid[d] = h; has |= h;
            }
            #pragma unroll
            for (int d = 0; d < 9; ++d) bd[d] = (bd[d] & ~has) | hid[d];
        }

        // ---------- unique 'v' (cross-band via shuffle) ----------
        {
            uint32_t hid[9], has = 0;
            #pragma unroll
            for (int d = 0; d < 9; ++d) {
                uint32_t w = bd[d];
                uint32_t q0 = colfold(w), m0 = colmaj2(w);
                uint32_t ex = q0 | (m0 << 9);
                uint32_t ea = (uint32_t)__shfl((int)ex, sl1, 64);
                uint32_t eb = (uint32_t)__shfl((int)ex, sl2, 64);
                uint32_t qa = ea & 0x1FFu, ma = ea >> 9;
                uint32_t qb = eb & 0x1FFu, mb = eb >> 9;
                uint32_t ge2 = m0 | ma | mb | (q0 & qa) | (q0 & qb) | (qa & qb);
                uint32_t ex1c = (q0 | qa | qb) & ~ge2;   // column total count == 1
                hid[d] = w & ((ex1c & q0) * 0x40201u);
                has |= hid[d];
            }
            #pragma unroll
            for (int d = 0; d < 9; ++d) bd[d] = (bd[d] & ~has) | hid[d];
        }

        // ---------- unique 'box' (band-local) ----------
        {
            uint32_t hid[9], has = 0;
            #pragma unroll
            for (int d = 0; d < 9; ++d) {
                uint32_t w = bd[d], h = 0;
                #pragma unroll
                for (int k = 0; k < 3; ++k) {
                    uint32_t x = w & (0x1C0E07u << (3 * k));
                    h |= (x & (x - 1u)) ? 0u : x;
                }
                hid[d] = h; has |= h;
            }
            #pragma unroll
            for (int d = 0; d < 9; ++d) bd[d] = (bd[d] & ~has) | hid[d];
        }

        // ---------- doubles 'v' twice (cross-band via shuffle) ----------
        #pragma unroll 1
        for (int rep = 0; rep < 2; ++rep) {
            uint32_t on = 0, tw = 0, fo = 0;
            #pragma unroll
            for (int d = 0; d < 9; ++d) {
                uint32_t c = on & bd[d];
                on ^= bd[d]; fo |= tw & c; tw ^= c;
            }
            uint32_t ex2 = tw & ~on & ~fo;
            uint32_t Q[9], K[9];
            #pragma unroll
            for (int d = 0; d < 9; ++d) { Q[d] = bd[d] & ex2; K[d] = 0u; }
            #pragma unroll
            for (int d1 = 0; d1 < 9; ++d1)
                #pragma unroll
                for (int d2 = d1 + 1; d2 < 9; ++d2) {
                    uint32_t P = Q[d1] & Q[d2];
                    uint32_t f0 = colfold(P), g0 = colmaj2(P);
                    uint32_t ex = f0 | (g0 << 9);
                    uint32_t ea = (uint32_t)__shfl((int)ex, sl1, 64);
                    uint32_t eb = (uint32_t)__shfl((int)ex, sl2, 64);
                    uint32_t fa = ea & 0x1FFu, ga = ea >> 9;
                    uint32_t fb = eb & 0x1FFu, gb = eb >> 9;
                    // columns with >=2 exact-pair cells across the full column
                    uint32_t dup = g0 | ga | gb | (f0 & fa) | (f0 & fb) | (fa & fb);
                    uint32_t sK = P & (dup * 0x40201u);
                    K[d1] |= sK; K[d2] |= sK;
                }
            #pragma unroll
            for (int d = 0; d < 9; ++d) {
                uint32_t kc = colfold(K[d]);
                uint32_t cols = kc | (uint32_t)__shfl((int)kc, sl1, 64)
                                   | (uint32_t)__shfl((int)kc, sl2, 64);
                uint32_t em = cols * 0x40201u;
                bd[d] = (bd[d] & ~em) | K[d];
            }
        }

        // ---------- doubles 'box' (band-local) ----------
        {
            uint32_t on = 0, tw = 0, fo = 0;
            #pragma unroll
            for (int d = 0; d < 9; ++d) {
                uint32_t c = on & bd[d];
                on ^= bd[d]; fo |= tw & c; tw ^= c;
            }
            uint32_t ex2 = tw & ~on & ~fo;
            uint32_t Q[9], K[9];
            #pragma unroll
            for (int d = 0; d < 9; ++d) { Q[d] = bd[d] & ex2; K[d] = 0u; }
            #pragma unroll
            for (int d1 = 0; d1 < 9; ++d1)
                #pragma unroll
                for (int d2 = d1 + 1; d2 < 9; ++d2) {
                    uint32_t P = Q[d1] & Q[d2];
                    #pragma unroll
                    for (int k = 0; k < 3; ++k) {
                        uint32_t m = P & (0x1C0E07u << (3 * k));
                        uint32_t s = (m & (m - 1u)) ? m : 0u;
                        K[d1] |= s; K[d2] |= s;
                    }
                }
            #pragma unroll
            for (int d = 0; d < 9; ++d)
                #pragma unroll
                for (int k = 0; k < 3; ++k) {
                    uint32_t bm = 0x1C0E07u << (3 * k);
                    uint32_t t = K[d] & bm;
                    uint32_t mask = t ? (~bm | t) : 0xFFFFFFFFu;
                    bd[d] &= mask;
                }
        }
    } // passes

    // ---------------- solved flag (AND across triple via shuffle) ----------------
    {
        uint32_t on = 0, tw = 0, fo = 0;
        #pragma unroll
        for (int d = 0; d < 9; ++d) {
            uint32_t c = on & bd[d];
            on ^= bd[d]; fo |= tw & c; tw ^= c;
        }
        uint32_t okb = ((on & ~tw & ~fo) == FULL27) ? 1u : 0u;
        uint32_t all = okb & (uint32_t)__shfl((int)okb, sl1, 64)
                           & (uint32_t)__shfl((int)okb, sl2, 64);
        if (valid && band == 0) solved[p] = all ? 1.0f : 0.0f;
    }

    // ---------------- EXPAND (fused, block-level): bit pool -> float4 stores ----------
    // Bit B of bpool == float blockP*729 + B. Zero -> barrier -> atomicOr
    // (dwords straddle adjacent lanes'/waves' 27-bit runs) -> barrier -> expand.
    for (int j = threadIdx.x; j < 1914; j += 256) bpool[j] = 0u;
    __syncthreads();
    if (valid) {
        const int pbit = (wv * 21 + trip) * 729;
        #pragma unroll
        for (int d = 0; d < 9; ++d) {
            int bitbase = pbit + d * 81 + band * 27;
            int di = bitbase >> 5;
            int sh = bitbase & 31;
            uint64_t both = (uint64_t)bd[d] << sh;
            atomicOr(&bpool[di], (uint32_t)both);
            atomicOr(&bpool[di + 1], (uint32_t)(both >> 32));
        }
    }
    __syncthreads();
    {
        int nvb = NB - blockP; if (nvb > 84) nvb = 84;       // 84, or 8 in last block
        const int limit4 = nvb * 729 / 4;                    // both cases divisible by 4
        float4* dst4 = (float4*)(out + (size_t)blockP * 729); // 61236 floats/block: 16B-aligned
        #pragma unroll 4
        for (int i = 0; i < 60; ++i) {
            int j = i * 256 + (int)threadIdx.x;
            if (j < limit4) {
                uint32_t nib = (bpool[j >> 3] >> ((j & 7) * 4)) & 0xFu;
                dst4[j] = make_float4((float)(nib & 1u), (float)((nib >> 1) & 1u),
                                      (float)((nib >> 2) & 1u), (float)((nib >> 3) & 1u));
            }
        }
    }
}

extern "C" void kernel_launch(void* const* d_in, const int* in_sizes, int n_in,
                              void* d_out, int out_size, void* d_ws, size_t ws_size,
                              hipStream_t stream) {
    const uint32_t* in = (const uint32_t*)d_in[0];   // float32 bits; nonzero <=> 1.0f
    float* out = (float*)d_out;
    float* solved = out + (size_t)NB * 729;
    uint32_t* packed = (uint32_t*)d_ws;              // NWORDS words = 3.54 MB

    pack_kernel<<<NWORDS / 256, 256, 0, stream>>>(in, packed);          // 3456 blocks
    // 84 puzzles per 256-thread block (21 per wave) -> ceil(32768/84) = 391 blocks
    solve_kernel<<<(NB + 83) / 84, 256, 0, stream>>>(packed, out, solved);
}

// Round 9
// 216.963 us; speedup vs baseline: 1.0860x; 1.0490x over previous
//
#include <hip/hip_runtime.h>
#include <stdint.h>

#define NB 32768
#define NPASS 4
#define FULL27 0x07FFFFFFu
#define NBF (NB * 729)     // total floats = 23,887,872

// Per-band bitboard: digit d, band b (rows 3b..3b+2), bit (r*9+c).
// BOX k mask within band: 0x1C0E07 << 3k ; COL c: 0x40201 << c ; ROW r: 0x1FF << 9r
// Flat float layout: puzzle p, digit d, band b, cell j  ==  p*729 + d*81 + b*27 + j.

__device__ __forceinline__ uint32_t colfold(uint32_t w) {
    return (w | (w >> 9) | (w >> 18)) & 0x1FFu;
}
__device__ __forceinline__ uint32_t colmaj2(uint32_t w) {   // columns with >=2 bits in band
    return ((w & (w >> 9)) | ((w | (w >> 9)) & (w >> 18))) & 0x1FFu;
}

// ---------------- FULLY FUSED: pack + solve + expand, one kernel ----------------
// Block = 256 threads = 4 waves; wave handles 21 puzzles (3 lanes per puzzle:
// trip = lane/3 = puzzle, band = lane%3; lane 63 idle). Phases:
//   PACK:   wave loads its 21*729 floats coalesced in 15 chunks of 16 rounds
//           (16 loads batched BEFORE 16 ballots -> 16-deep MLP; r3's fused pack
//           failed on 1-deep dependent load->ballot chains), ballot bits land in
//           a wave-private 480-dword LDS strip.
//   SOLVE:  validated r6/r8 logic, cross-band exchange via __shfl, no barriers.
//   EXPAND: validated r8 block-pool float4 writeback.
__global__ __launch_bounds__(256, 1)
void sudoku_kernel(const uint32_t* __restrict__ in, float* __restrict__ out,
                   float* __restrict__ solved) {
    __shared__ uint32_t bpool[1920];        // pack: 4 strips x 480 dw; expand: 1914 dw
    const int lane = threadIdx.x & 63;
    const int wv   = threadIdx.x >> 6;
    const int trip = lane / 3;              // 0..21 (21 = idle lane 63)
    const int band = lane - trip * 3;
    const int bo1 = band == 2 ? 0 : band + 1;
    const int bo2 = band == 0 ? 2 : band - 1;
    int sl1 = trip * 3 + bo1; if (sl1 > 63) sl1 = 63;   // partner lanes
    int sl2 = trip * 3 + bo2; if (sl2 > 63) sl2 = 63;
    const int blockP = blockIdx.x * 84;                 // first puzzle of block
    const int pb = blockP + wv * 21;                    // first puzzle of wave
    const int p = pb + trip;
    const bool valid = (trip < 21) && (p < NB);

    // ---------------- PACK: coalesced loads -> ballot -> wave-private LDS strip ----
    // Wave-local bit j == input float pb*729 + j (j in [0, 15309)).
    {
        const int base = pb * 729;                      // < 24M, fits int
        uint32_t* mypool = &bpool[wv * 480];
        #pragma unroll 1
        for (int c = 0; c < 15; ++c) {
            uint32_t v[16];
            #pragma unroll
            for (int j = 0; j < 16; ++j) {
                int gi = base + (c * 16 + j) * 64 + lane;
                if (gi >= NBF) gi = NBF - 1;            // tail-block clamp (bits unused)
                v[j] = in[gi];
            }
            #pragma unroll
            for (int j = 0; j < 16; ++j) {
                unsigned long long m = __ballot(v[j] != 0u);
                if (lane == 0) {
                    int r = c * 16 + j;
                    mypool[2 * r]     = (uint32_t)m;
                    mypool[2 * r + 1] = (uint32_t)(m >> 32);
                }
            }
        }
    }
    __syncthreads();

    // ---------------- EXTRACT: 9 band-words for this lane's puzzle ----------------
    uint32_t bd[9];
    {
        const uint32_t* mypool = &bpool[wv * 480];
        const int tx = trip > 20 ? 20 : trip;           // keep idle lane 63 in-bounds
        const int bb0 = tx * 729 + band * 27;
        #pragma unroll
        for (int d = 0; d < 9; ++d) {
            int bb = bb0 + d * 81;
            int di = bb >> 5, sh = bb & 31;
            uint64_t both = (uint64_t)mypool[di] | ((uint64_t)mypool[di + 1] << 32);
            bd[d] = (uint32_t)(both >> sh) & FULL27;
        }
    }
    __syncthreads();    // all extraction done before anyone zeroes the pool later

    // ---------------- SOLVE (validated r6/r8 logic, unchanged) ----------------
    #pragma unroll 1
    for (int pass = 0; pass < NPASS; ++pass) {
        // ---------- filter 'box' (band-local) ----------
        {
            uint32_t on = 0, tw = 0, fo = 0;
            #pragma unroll
            for (int d = 0; d < 9; ++d) {
                uint32_t c = on & bd[d];
                on ^= bd[d]; fo |= tw & c; tw ^= c;
            }
            uint32_t ex1 = on & ~tw & ~fo;
            #pragma unroll
            for (int d = 0; d < 9; ++d) {
                uint32_t s = bd[d] & ex1;
                #pragma unroll
                for (int k = 0; k < 3; ++k) {
                    uint32_t bm = 0x1C0E07u << (3 * k);
                    uint32_t sm = s & bm;
                    uint32_t multi = sm & (sm - 1u);
                    uint32_t keep = (sm == 0u) ? 0xFFFFFFFFu : (~bm | (multi ? 0u : sm));
                    bd[d] &= keep;
                }
            }
        }

        // ---------- pointing 'h' (band-local) ----------
        #pragma unroll
        for (int d = 0; d < 9; ++d) {
            uint32_t w = bd[d];
            uint32_t t = (w | (w >> 1) | (w >> 2)) & 0x01249249u;
            uint32_t sum = (t & 0x1FFu) + ((t >> 9) & 0x1FFu) + ((t >> 18) & 0x1FFu);
            uint32_t single = sum & ~(sum >> 1) & 0x49u;
            uint32_t point = t & (single * 0x40201u);
            uint32_t clearm = 0;
            #pragma unroll
            for (int r = 0; r < 3; ++r) {
                uint32_t pr = (point >> (9 * r)) & 0x1FFu;
                uint32_t multi = pr & (pr - 1u);
                uint32_t segkeep = multi ? 0u : pr * 7u;
                uint32_t rc = pr ? ((0x1FFu & ~segkeep) << (9 * r)) : 0u;
                clearm |= rc;
            }
            bd[d] = w & ~clearm;
        }

        // ---------- pointing 'v' (cross-band via shuffle) ----------
        {
            uint32_t pnt[9];
            #pragma unroll
            for (int d = 0; d < 9; ++d) {
                uint32_t w = bd[d];
                uint32_t q = colfold(w);
                uint32_t u = (q & 0x49u) + ((q >> 1) & 0x49u) + ((q >> 2) & 0x49u);
                uint32_t single = u & ~(u >> 1) & 0x49u;
                pnt[d] = q & (single * 7u);
            }
            #pragma unroll
            for (int d = 0; d < 9; ++d) {
                uint32_t o = (uint32_t)__shfl((int)pnt[d], sl1, 64) |
                             (uint32_t)__shfl((int)pnt[d], sl2, 64);
                bd[d] &= ~(o * 0x40201u);
            }
        }

        // ---------- unique 'h' (band-local) ----------
        {
            uint32_t hid[9], has = 0;
            #pragma unroll
            for (int d = 0; d < 9; ++d) {
                uint32_t w = bd[d], h = 0;
                #pragma unroll
                for (int r = 0; r < 3; ++r) {
                    uint32_t x = w & (0x1FFu << (9 * r));
                    h |= (x & (x - 1u)) ? 0u : x;
                }
                hid[d] = h; has |= h;
            }
            #pragma unroll
            for (int d = 0; d < 9; ++d) bd[d] = (bd[d] & ~has) | hid[d];
        }

        // ---------- unique 'v' (cross-band via shuffle) ----------
        {
            uint32_t hid[9], has = 0;
            #pragma unroll
            for (int d = 0; d < 9; ++d) {
                uint32_t w = bd[d];
                uint32_t q0 = colfold(w), m0 = colmaj2(w);
                uint32_t ex = q0 | (m0 << 9);
                uint32_t ea = (uint32_t)__shfl((int)ex, sl1, 64);
                uint32_t eb = (uint32_t)__shfl((int)ex, sl2, 64);
                uint32_t qa = ea & 0x1FFu, ma = ea >> 9;
                uint32_t qb = eb & 0x1FFu, mb = eb >> 9;
                uint32_t ge2 = m0 | ma | mb | (q0 & qa) | (q0 & qb) | (qa & qb);
                uint32_t ex1c = (q0 | qa | qb) & ~ge2;   // column total count == 1
                hid[d] = w & ((ex1c & q0) * 0x40201u);
                has |= hid[d];
            }
            #pragma unroll
            for (int d = 0; d < 9; ++d) bd[d] = (bd[d] & ~has) | hid[d];
        }

        // ---------- unique 'box' (band-local) ----------
        {
            uint32_t hid[9], has = 0;
            #pragma unroll
            for (int d = 0; d < 9; ++d) {
                uint32_t w = bd[d], h = 0;
                #pragma unroll
                for (int k = 0; k < 3; ++k) {
                    uint32_t x = w & (0x1C0E07u << (3 * k));
                    h |= (x & (x - 1u)) ? 0u : x;
                }
                hid[d] = h; has |= h;
            }
            #pragma unroll
            for (int d = 0; d < 9; ++d) bd[d] = (bd[d] & ~has) | hid[d];
        }

        // ---------- doubles 'v' twice (cross-band via shuffle) ----------
        #pragma unroll 1
        for (int rep = 0; rep < 2; ++rep) {
            uint32_t on = 0, tw = 0, fo = 0;
            #pragma unroll
            for (int d = 0; d < 9; ++d) {
                uint32_t c = on & bd[d];
                on ^= bd[d]; fo |= tw & c; tw ^= c;
            }
            uint32_t ex2 = tw & ~on & ~fo;
            uint32_t Q[9], K[9];
            #pragma unroll
            for (int d = 0; d < 9; ++d) { Q[d] = bd[d] & ex2; K[d] = 0u; }
            #pragma unroll
            for (int d1 = 0; d1 < 9; ++d1)
                #pragma unroll
                for (int d2 = d1 + 1; d2 < 9; ++d2) {
                    uint32_t P = Q[d1] & Q[d2];
                    uint32_t f0 = colfold(P), g0 = colmaj2(P);
                    uint32_t ex = f0 | (g0 << 9);
                    uint32_t ea = (uint32_t)__shfl((int)ex, sl1, 64);
                    uint32_t eb = (uint32_t)__shfl((int)ex, sl2, 64);
                    uint32_t fa = ea & 0x1FFu, ga = ea >> 9;
                    uint32_t fb = eb & 0x1FFu, gb = eb >> 9;
                    // columns with >=2 exact-pair cells across the full column
                    uint32_t dup = g0 | ga | gb | (f0 & fa) | (f0 & fb) | (fa & fb);
                    uint32_t sK = P & (dup * 0x40201u);
                    K[d1] |= sK; K[d2] |= sK;
                }
            #pragma unroll
            for (int d = 0; d < 9; ++d) {
                uint32_t kc = colfold(K[d]);
                uint32_t cols = kc | (uint32_t)__shfl((int)kc, sl1, 64)
                                   | (uint32_t)__shfl((int)kc, sl2, 64);
                uint32_t em = cols * 0x40201u;
                bd[d] = (bd[d] & ~em) | K[d];
            }
        }

        // ---------- doubles 'box' (band-local) ----------
        {
            uint32_t on = 0, tw = 0, fo = 0;
            #pragma unroll
            for (int d = 0; d < 9; ++d) {
                uint32_t c = on & bd[d];
                on ^= bd[d]; fo |= tw & c; tw ^= c;
            }
            uint32_t ex2 = tw & ~on & ~fo;
            uint32_t Q[9], K[9];
            #pragma unroll
            for (int d = 0; d < 9; ++d) { Q[d] = bd[d] & ex2; K[d] = 0u; }
            #pragma unroll
            for (int d1 = 0; d1 < 9; ++d1)
                #pragma unroll
                for (int d2 = d1 + 1; d2 < 9; ++d2) {
                    uint32_t P = Q[d1] & Q[d2];
                    #pragma unroll
                    for (int k = 0; k < 3; ++k) {
                        uint32_t m = P & (0x1C0E07u << (3 * k));
                        uint32_t s = (m & (m - 1u)) ? m : 0u;
                        K[d1] |= s; K[d2] |= s;
                    }
                }
            #pragma unroll
            for (int d = 0; d < 9; ++d)
                #pragma unroll
                for (int k = 0; k < 3; ++k) {
                    uint32_t bm = 0x1C0E07u << (3 * k);
                    uint32_t t = K[d] & bm;
                    uint32_t mask = t ? (~bm | t) : 0xFFFFFFFFu;
                    bd[d] &= mask;
                }
        }
    } // passes

    // ---------------- solved flag (AND across triple via shuffle) ----------------
    {
        uint32_t on = 0, tw = 0, fo = 0;
        #pragma unroll
        for (int d = 0; d < 9; ++d) {
            uint32_t c = on & bd[d];
            on ^= bd[d]; fo |= tw & c; tw ^= c;
        }
        uint32_t okb = ((on & ~tw & ~fo) == FULL27) ? 1u : 0u;
        uint32_t all = okb & (uint32_t)__shfl((int)okb, sl1, 64)
                           & (uint32_t)__shfl((int)okb, sl2, 64);
        if (valid && band == 0) solved[p] = all ? 1.0f : 0.0f;
    }

    // ---------------- EXPAND (validated r8): block pool -> float4 stores ----------
    // Bit B of bpool == float blockP*729 + B. Zero -> barrier -> atomicOr -> barrier.
    for (int j = threadIdx.x; j < 1914; j += 256) bpool[j] = 0u;
    __syncthreads();
    if (valid) {
        const int pbit = (wv * 21 + trip) * 729;
        #pragma unroll
        for (int d = 0; d < 9; ++d) {
            int bitbase = pbit + d * 81 + band * 27;
            int di = bitbase >> 5;
            int sh = bitbase & 31;
            uint64_t both = (uint64_t)bd[d] << sh;
            atomicOr(&bpool[di], (uint32_t)both);
            atomicOr(&bpool[di + 1], (uint32_t)(both >> 32));
        }
    }
    __syncthreads();
    {
        int nvb = NB - blockP; if (nvb > 84) nvb = 84;       // 84, or 8 in last block
        const int limit4 = nvb * 729 / 4;                    // both cases divisible by 4
        float4* dst4 = (float4*)(out + (size_t)blockP * 729); // 61236 floats/block: 16B-aligned
        #pragma unroll 4
        for (int i = 0; i < 60; ++i) {
            int j = i * 256 + (int)threadIdx.x;
            if (j < limit4) {
                uint32_t nib = (bpool[j >> 3] >> ((j & 7) * 4)) & 0xFu;
                dst4[j] = make_float4((float)(nib & 1u), (float)((nib >> 1) & 1u),
                                      (float)((nib >> 2) & 1u), (float)((nib >> 3) & 1u));
            }
        }
    }
}

extern "C" void kernel_launch(void* const* d_in, const int* in_sizes, int n_in,
                              void* d_out, int out_size, void* d_ws, size_t ws_size,
                              hipStream_t stream) {
    const uint32_t* in = (const uint32_t*)d_in[0];   // float32 bits; nonzero <=> 1.0f
    float* out = (float*)d_out;
    float* solved = out + (size_t)NB * 729;
    // 84 puzzles per 256-thread block (21 per wave) -> ceil(32768/84) = 391 blocks
    sudoku_kernel<<<(NB + 83) / 84, 256, 0, stream>>>(in, out, solved);
}

// Round 10
// 216.845 us; speedup vs baseline: 1.0866x; 1.0005x over previous
//
#include <hip/hip_runtime.h>
#include <stdint.h>

#define NB 32768
#define NPASS 4
#define FULL27 0x07FFFFFFu
#define NBF (NB * 729)       // total floats = 23,887,872
#define NBF4 (NBF / 4)       // total uint4s = 5,971,968

// Per-band bitboard: digit d, band b (rows 3b..3b+2), bit (r*9+c).
// BOX k mask within band: 0x1C0E07 << 3k ; COL c: 0x40201 << c ; ROW r: 0x1FF << 9r
// Flat float layout: puzzle p, digit d, band b, cell j  ==  p*729 + d*81 + b*27 + j.

__device__ __forceinline__ uint32_t colfold(uint32_t w) {
    return (w | (w >> 9) | (w >> 18)) & 0x1FFu;
}
__device__ __forceinline__ uint32_t colmaj2(uint32_t w) {   // columns with >=2 bits in band
    return ((w & (w >> 9)) | ((w | (w >> 9)) & (w >> 18))) & 0x1FFu;
}
__device__ __forceinline__ uint32_t spread8(uint32_t x) {   // 8 bits -> stride-4 positions
    x = (x | (x << 12)) & 0x000F000Fu;
    x = (x | (x << 6))  & 0x03030303u;
    x = (x | (x << 3))  & 0x11111111u;
    return x;
}

// ---------------- FULLY FUSED: pack + solve + expand, one kernel ----------------
// Block = 256 threads = 4 waves; 84 puzzles/block (21/wave, 3 lanes per puzzle:
// trip = lane/3, band = lane%3; lane 63 idle).
//   PACK:   uint4 loads (16 B/lane — r9 post-mortem: scalar-dword global access
//           caps at ~2.6 TB/s on this part, float4 ~6+ TB/s). Block window =
//           15309 uint4s (16B-aligned; per-wave windows are NOT). Wave wv does
//           groups g ≡ wv (mod 4); 4 ballots/group; lanes 0-7 bit-interleave
//           the 4 masks into 8 input-order pool dwords via spread8.
//   SOLVE:  validated r6/r8 logic, cross-band exchange via __shfl, no barriers.
//   EXPAND: validated r8 block-pool float4 writeback.
__global__ __launch_bounds__(256, 1)
void sudoku_kernel(const uint32_t* __restrict__ in, float* __restrict__ out,
                   float* __restrict__ solved) {
    __shared__ uint32_t bpool[1920];        // pack: 240 groups x 8 dw; expand: 1914 dw
    const int lane = threadIdx.x & 63;
    const int wv   = threadIdx.x >> 6;
    const int trip = lane / 3;              // 0..21 (21 = idle lane 63)
    const int band = lane - trip * 3;
    const int bo1 = band == 2 ? 0 : band + 1;
    const int bo2 = band == 0 ? 2 : band - 1;
    int sl1 = trip * 3 + bo1; if (sl1 > 63) sl1 = 63;   // partner lanes
    int sl2 = trip * 3 + bo2; if (sl2 > 63) sl2 = 63;
    const int blockP = blockIdx.x * 84;                 // first puzzle of block
    const int p = blockP + wv * 21 + trip;
    const bool valid = (trip < 21) && (p < NB);

    // ---------------- PACK: uint4 loads -> 4 ballots -> interleaved pool dwords ----
    // Block bit j == input float blockP*729 + j. Group g covers floats
    // [g*256, g*256+256) of the block window -> pool dwords 8g..8g+7.
    {
        const uint4* src4 = (const uint4*)in;
        const int base4 = blockIdx.x * 15309;           // block window in uint4s
        #pragma unroll 1
        for (int c = 0; c < 15; ++c) {                  // 15 chunks x 4 groups/wave
            uint4 v[4];
            #pragma unroll
            for (int j = 0; j < 4; ++j) {
                int g = (c * 4 + j) * 4 + wv;           // group index, wave-interleaved
                int gi = base4 + g * 64 + lane;
                if (gi > NBF4 - 1) gi = NBF4 - 1;       // tail-block clamp (bits unused)
                v[j] = src4[gi];
            }
            #pragma unroll
            for (int j = 0; j < 4; ++j) {
                int g = (c * 4 + j) * 4 + wv;
                unsigned long long m0 = __ballot(v[j].x != 0u);
                unsigned long long m1 = __ballot(v[j].y != 0u);
                unsigned long long m2 = __ballot(v[j].z != 0u);
                unsigned long long m3 = __ballot(v[j].w != 0u);
                if (lane < 8) {
                    int sh = lane * 8;
                    uint32_t b0 = (uint32_t)(m0 >> sh) & 0xFFu;
                    uint32_t b1 = (uint32_t)(m1 >> sh) & 0xFFu;
                    uint32_t b2 = (uint32_t)(m2 >> sh) & 0xFFu;
                    uint32_t b3 = (uint32_t)(m3 >> sh) & 0xFFu;
                    bpool[8 * g + lane] = spread8(b0) | (spread8(b1) << 1)
                                        | (spread8(b2) << 2) | (spread8(b3) << 3);
                }
            }
        }
    }
    __syncthreads();

    // ---------------- EXTRACT: 9 band-words for this lane's puzzle ----------------
    uint32_t bd[9];
    {
        const int tx = trip > 20 ? 20 : trip;           // keep idle lane 63 in-bounds
        const int lp = wv * 21 + tx;                    // block-local puzzle 0..83
        const int bb0 = lp * 729 + band * 27;
        #pragma unroll
        for (int d = 0; d < 9; ++d) {
            int bb = bb0 + d * 81;
            int di = bb >> 5, sh = bb & 31;
            uint64_t both = (uint64_t)bpool[di] | ((uint64_t)bpool[di + 1] << 32);
            bd[d] = (uint32_t)(both >> sh) & FULL27;
        }
    }
    __syncthreads();    // all extraction done before anyone zeroes the pool later

    // ---------------- SOLVE (validated r6/r8 logic, unchanged) ----------------
    #pragma unroll 1
    for (int pass = 0; pass < NPASS; ++pass) {
        // ---------- filter 'box' (band-local) ----------
        {
            uint32_t on = 0, tw = 0, fo = 0;
            #pragma unroll
            for (int d = 0; d < 9; ++d) {
                uint32_t c = on & bd[d];
                on ^= bd[d]; fo |= tw & c; tw ^= c;
            }
            uint32_t ex1 = on & ~tw & ~fo;
            #pragma unroll
            for (int d = 0; d < 9; ++d) {
                uint32_t s = bd[d] & ex1;
                #pragma unroll
                for (int k = 0; k < 3; ++k) {
                    uint32_t bm = 0x1C0E07u << (3 * k);
                    uint32_t sm = s & bm;
                    uint32_t multi = sm & (sm - 1u);
                    uint32_t keep = (sm == 0u) ? 0xFFFFFFFFu : (~bm | (multi ? 0u : sm));
                    bd[d] &= keep;
                }
            }
        }

        // ---------- pointing 'h' (band-local) ----------
        #pragma unroll
        for (int d = 0; d < 9; ++d) {
            uint32_t w = bd[d];
            uint32_t t = (w | (w >> 1) | (w >> 2)) & 0x01249249u;
            uint32_t sum = (t & 0x1FFu) + ((t >> 9) & 0x1FFu) + ((t >> 18) & 0x1FFu);
            uint32_t single = sum & ~(sum >> 1) & 0x49u;
            uint32_t point = t & (single * 0x40201u);
            uint32_t clearm = 0;
            #pragma unroll
            for (int r = 0; r < 3; ++r) {
                uint32_t pr = (point >> (9 * r)) & 0x1FFu;
                uint32_t multi = pr & (pr - 1u);
                uint32_t segkeep = multi ? 0u : pr * 7u;
                uint32_t rc = pr ? ((0x1FFu & ~segkeep) << (9 * r)) : 0u;
                clearm |= rc;
            }
            bd[d] = w & ~clearm;
        }

        // ---------- pointing 'v' (cross-band via shuffle) ----------
        {
            uint32_t pnt[9];
            #pragma unroll
            for (int d = 0; d < 9; ++d) {
                uint32_t w = bd[d];
                uint32_t q = colfold(w);
                uint32_t u = (q & 0x49u) + ((q >> 1) & 0x49u) + ((q >> 2) & 0x49u);
                uint32_t single = u & ~(u >> 1) & 0x49u;
                pnt[d] = q & (single * 7u);
            }
            #pragma unroll
            for (int d = 0; d < 9; ++d) {
                uint32_t o = (uint32_t)__shfl((int)pnt[d], sl1, 64) |
                             (uint32_t)__shfl((int)pnt[d], sl2, 64);
                bd[d] &= ~(o * 0x40201u);
            }
        }

        // ---------- unique 'h' (band-local) ----------
        {
            uint32_t hid[9], has = 0;
            #pragma unroll
            for (int d = 0; d < 9; ++d) {
                uint32_t w = bd[d], h = 0;
                #pragma unroll
                for (int r = 0; r < 3; ++r) {
                    uint32_t x = w & (0x1FFu << (9 * r));
                    h |= (x & (x - 1u)) ? 0u : x;
                }
                hid[d] = h; has |= h;
            }
            #pragma unroll
            for (int d = 0; d < 9; ++d) bd[d] = (bd[d] & ~has) | hid[d];
        }

        // ---------- unique 'v' (cross-band via shuffle) ----------
        {
            uint32_t hid[9], has = 0;
            #pragma unroll
            for (int d = 0; d < 9; ++d) {
                uint32_t w = bd[d];
                uint32_t q0 = colfold(w), m0 = colmaj2(w);
                uint32_t ex = q0 | (m0 << 9);
                uint32_t ea = (uint32_t)__shfl((int)ex, sl1, 64);
                uint32_t eb = (uint32_t)__shfl((int)ex, sl2, 64);
                uint32_t qa = ea & 0x1FFu, ma = ea >> 9;
                uint32_t qb = eb & 0x1FFu, mb = eb >> 9;
                uint32_t ge2 = m0 | ma | mb | (q0 & qa) | (q0 & qb) | (qa & qb);
                uint32_t ex1c = (q0 | qa | qb) & ~ge2;   // column total count == 1
                hid[d] = w & ((ex1c & q0) * 0x40201u);
                has |= hid[d];
            }
            #pragma unroll
            for (int d = 0; d < 9; ++d) bd[d] = (bd[d] & ~has) | hid[d];
        }

        // ---------- unique 'box' (band-local) ----------
        {
            uint32_t hid[9], has = 0;
            #pragma unroll
            for (int d = 0; d < 9; ++d) {
                uint32_t w = bd[d], h = 0;
                #pragma unroll
                for (int k = 0; k < 3; ++k) {
                    uint32_t x = w & (0x1C0E07u << (3 * k));
                    h |= (x & (x - 1u)) ? 0u : x;
                }
                hid[d] = h; has |= h;
            }
            #pragma unroll
            for (int d = 0; d < 9; ++d) bd[d] = (bd[d] & ~has) | hid[d];
        }

        // ---------- doubles 'v' twice (cross-band via shuffle) ----------
        #pragma unroll 1
        for (int rep = 0; rep < 2; ++rep) {
            uint32_t on = 0, tw = 0, fo = 0;
            #pragma unroll
            for (int d = 0; d < 9; ++d) {
                uint32_t c = on & bd[d];
                on ^= bd[d]; fo |= tw & c; tw ^= c;
            }
            uint32_t ex2 = tw & ~on & ~fo;
            uint32_t Q[9], K[9];
            #pragma unroll
            for (int d = 0; d < 9; ++d) { Q[d] = bd[d] & ex2; K[d] = 0u; }
            #pragma unroll
            for (int d1 = 0; d1 < 9; ++d1)
                #pragma unroll
                for (int d2 = d1 + 1; d2 < 9; ++d2) {
                    uint32_t P = Q[d1] & Q[d2];
                    uint32_t f0 = colfold(P), g0 = colmaj2(P);
                    uint32_t ex = f0 | (g0 << 9);
                    uint32_t ea = (uint32_t)__shfl((int)ex, sl1, 64);
                    uint32_t eb = (uint32_t)__shfl((int)ex, sl2, 64);
                    uint32_t fa = ea & 0x1FFu, ga = ea >> 9;
                    uint32_t fb = eb & 0x1FFu, gb = eb >> 9;
                    // columns with >=2 exact-pair cells across the full column
                    uint32_t dup = g0 | ga | gb | (f0 & fa) | (f0 & fb) | (fa & fb);
                    uint32_t sK = P & (dup * 0x40201u);
                    K[d1] |= sK; K[d2] |= sK;
                }
            #pragma unroll
            for (int d = 0; d < 9; ++d) {
                uint32_t kc = colfold(K[d]);
                uint32_t cols = kc | (uint32_t)__shfl((int)kc, sl1, 64)
                                   | (uint32_t)__shfl((int)kc, sl2, 64);
                uint32_t em = cols * 0x40201u;
                bd[d] = (bd[d] & ~em) | K[d];
            }
        }

        // ---------- doubles 'box' (band-local) ----------
        {
            uint32_t on = 0, tw = 0, fo = 0;
            #pragma unroll
            for (int d = 0; d < 9; ++d) {
                uint32_t c = on & bd[d];
                on ^= bd[d]; fo |= tw & c; tw ^= c;
            }
            uint32_t ex2 = tw & ~on & ~fo;
            uint32_t Q[9], K[9];
            #pragma unroll
            for (int d = 0; d < 9; ++d) { Q[d] = bd[d] & ex2; K[d] = 0u; }
            #pragma unroll
            for (int d1 = 0; d1 < 9; ++d1)
                #pragma unroll
                for (int d2 = d1 + 1; d2 < 9; ++d2) {
                    uint32_t P = Q[d1] & Q[d2];
                    #pragma unroll
                    for (int k = 0; k < 3; ++k) {
                        uint32_t m = P & (0x1C0E07u << (3 * k));
                        uint32_t s = (m & (m - 1u)) ? m : 0u;
                        K[d1] |= s; K[d2] |= s;
                    }
                }
            #pragma unroll
            for (int d = 0; d < 9; ++d)
                #pragma unroll
                for (int k = 0; k < 3; ++k) {
                    uint32_t bm = 0x1C0E07u << (3 * k);
                    uint32_t t = K[d] & bm;
                    uint32_t mask = t ? (~bm | t) : 0xFFFFFFFFu;
                    bd[d] &= mask;
                }
        }
    } // passes

    // ---------------- solved flag (AND across triple via shuffle) ----------------
    {
        uint32_t on = 0, tw = 0, fo = 0;
        #pragma unroll
        for (int d = 0; d < 9; ++d) {
            uint32_t c = on & bd[d];
            on ^= bd[d]; fo |= tw & c; tw ^= c;
        }
        uint32_t okb = ((on & ~tw & ~fo) == FULL27) ? 1u : 0u;
        uint32_t all = okb & (uint32_t)__shfl((int)okb, sl1, 64)
                           & (uint32_t)__shfl((int)okb, sl2, 64);
        if (valid && band == 0) solved[p] = all ? 1.0f : 0.0f;
    }

    // ---------------- EXPAND (validated r8): block pool -> float4 stores ----------
    // Bit B of bpool == float blockP*729 + B. Zero -> barrier -> atomicOr -> barrier.
    for (int j = threadIdx.x; j < 1914; j += 256) bpool[j] = 0u;
    __syncthreads();
    if (valid) {
        const int pbit = (wv * 21 + trip) * 729;
        #pragma unroll
        for (int d = 0; d < 9; ++d) {
            int bitbase = pbit + d * 81 + band * 27;
            int di = bitbase >> 5;
            int sh = bitbase & 31;
            uint64_t both = (uint64_t)bd[d] << sh;
            atomicOr(&bpool[di], (uint32_t)both);
            atomicOr(&bpool[di + 1], (uint32_t)(both >> 32));
        }
    }
    __syncthreads();
    {
        int nvb = NB - blockP; if (nvb > 84) nvb = 84;       // 84, or 8 in last block
        const int limit4 = nvb * 729 / 4;                    // both cases divisible by 4
        float4* dst4 = (float4*)(out + (size_t)blockP * 729); // 61236 floats/block: 16B-aligned
        #pragma unroll 4
        for (int i = 0; i < 60; ++i) {
            int j = i * 256 + (int)threadIdx.x;
            if (j < limit4) {
                uint32_t nib = (bpool[j >> 3] >> ((j & 7) * 4)) & 0xFu;
                dst4[j] = make_float4((float)(nib & 1u), (float)((nib >> 1) & 1u),
                                      (float)((nib >> 2) & 1u), (float)((nib >> 3) & 1u));
            }
        }
    }
}

extern "C" void kernel_launch(void* const* d_in, const int* in_sizes, int n_in,
                              void* d_out, int out_size, void* d_ws, size_t ws_size,
                              hipStream_t stream) {
    const uint32_t* in = (const uint32_t*)d_in[0];   // float32 bits; nonzero <=> 1.0f
    float* out = (float*)d_out;
    float* solved = out + (size_t)NB * 729;
    // 84 puzzles per 256-thread block (21 per wave) -> ceil(32768/84) = 391 blocks
    sudoku_kernel<<<(NB + 83) / 84, 256, 0, stream>>>(in, out, solved);
}